// Round 4
// baseline (1336.133 us; speedup 1.0000x reference)
//
#include <hip/hip_runtime.h>

// T=1024, B=256, I=256, H=256, fp32 in/out.
// out = outputs [T,B,H] flat, then final state [B,H].
//
// Kernel A: f16 MFMA xw = X@W_xh+b. 512-thr blocks (8 waves x 32 cols = all
//   256 cols; X tile L1-shared across waves, no y-duplication -> X HBM once).
//   16 contiguous row-tiles per block, register double-buffer prefetch
//   (bufA/bufB) hides HBM latency. Writes ws f16 permuted for kernel B.
// Kernel B: 32 blocks x 8 waves. Waves 0-3 = batch group b0..b0+3, waves
//   4-7 = b0+4..b0+7 (separate LDS state) -> 2 independent recurrences per
//   SIMD (was 1 wave/SIMD, all latency exposed). xw from ws (alias-free ->
//   counted vmcnt), raw s_barrier, vmcnt never drained.

#define TT 1024
#define BB 256
#define HH 256

typedef __attribute__((ext_vector_type(8))) _Float16 f16x8;
typedef __attribute__((ext_vector_type(4))) _Float16 f16x4;
typedef __attribute__((ext_vector_type(2))) _Float16 f16x2;
typedef __attribute__((ext_vector_type(4))) float f32x4;

__device__ __forceinline__ float fast_tanh(float x) {
    float e = __expf(2.0f * x);
    return 1.0f - 2.0f * __builtin_amdgcn_rcpf(e + 1.0f);
}

// ---------------- Kernel A: xw = X @ W_xh + b ----------------
#define AT 16  // row-tiles per block; grid = 16384/AT = 1024 blocks

#define XLOAD(BUF, RT)                                                            \
    {                                                                             \
        const float* xp_ = X + ((size_t)(RT)*16 + c) * HH + quad * 8;             \
        _Pragma("unroll")                                                         \
        for (int kt = 0; kt < 8; kt++) {                                          \
            BUF[2 * kt]     = *(const float4*)(xp_ + kt * 32);                    \
            BUF[2 * kt + 1] = *(const float4*)(xp_ + kt * 32 + 4);                \
        }                                                                         \
    }

#define XCOMP(BUF, RT)                                                            \
    {                                                                             \
        f16x8 af[8];                                                              \
        _Pragma("unroll")                                                         \
        for (int kt = 0; kt < 8; kt++) {                                          \
            float4 lo = BUF[2 * kt], hi = BUF[2 * kt + 1];                        \
            f16x8 v;                                                              \
            v[0] = (_Float16)lo.x; v[1] = (_Float16)lo.y;                         \
            v[2] = (_Float16)lo.z; v[3] = (_Float16)lo.w;                         \
            v[4] = (_Float16)hi.x; v[5] = (_Float16)hi.y;                         \
            v[6] = (_Float16)hi.z; v[7] = (_Float16)hi.w;                         \
            af[kt] = v;                                                           \
        }                                                                         \
        f32x4 acc[2];                                                             \
        _Pragma("unroll")                                                         \
        for (int nt = 0; nt < 2; nt++) acc[nt] = (f32x4){0.f, 0.f, 0.f, 0.f};     \
        _Pragma("unroll")                                                         \
        for (int kt = 0; kt < 8; kt++)                                            \
            _Pragma("unroll")                                                     \
            for (int nt = 0; nt < 2; nt++)                                        \
                acc[nt] = __builtin_amdgcn_mfma_f32_16x16x32_f16(af[kt], bfx[nt], acc[nt], 0, 0, 0), \
                bfx[nt] = bfx[nt]; /* keep macro simple */                        \
        (void)0;                                                                  \
    }

template <bool TOWS>
__global__ __launch_bounds__(512, 1) void xw_gemm(const float* __restrict__ X,
                                                  const float* __restrict__ W,
                                                  const float* __restrict__ bh,
                                                  _Float16* __restrict__ ws,
                                                  float* __restrict__ out) {
    const int tid  = threadIdx.x;
    const int lane = tid & 63;
    const int wave = tid >> 6;        // 0..7, cols [wave*32, wave*32+32)
    const int c    = lane & 15;
    const int quad = lane >> 4;
    const int nb   = wave * 32;

    // B frags: bfx[nt][kt][j] = W[kt*32+quad*8+j][nb+nt*16+c]  (64 VGPR)
    f16x8 bfx[2][8];
#pragma unroll
    for (int nt = 0; nt < 2; nt++) {
        const int n = nb + nt * 16 + c;
#pragma unroll
        for (int kt = 0; kt < 8; kt++) {
            const int kb = kt * 32 + quad * 8;
            f16x8 v;
#pragma unroll
            for (int j = 0; j < 8; j++)
                v[j] = (_Float16)W[(size_t)(kb + j) * HH + n];
            bfx[nt][kt] = v;
        }
    }
    float bb[2];
#pragma unroll
    for (int nt = 0; nt < 2; nt++) bb[nt] = bh[nb + nt * 16 + c];

    // packed col index for B's f16x4 read: col n -> (n>>6)*64+(n&15)*4+((n>>4)&3)
    const int pbase = (wave >> 1) * 64 + c * 4 + (wave & 1) * 2;

    const int base = blockIdx.x * AT;

    float4 bufA[16], bufB[16];
    XLOAD(bufA, base)

#pragma unroll 1
    for (int k = 0; k < AT; k += 2) {
        XLOAD(bufB, base + k + 1)
        // ---- compute bufA (tile base+k) ----
        {
            f16x8 af[8];
#pragma unroll
            for (int kt = 0; kt < 8; kt++) {
                float4 lo = bufA[2 * kt], hi = bufA[2 * kt + 1];
                f16x8 v;
                v[0] = (_Float16)lo.x; v[1] = (_Float16)lo.y;
                v[2] = (_Float16)lo.z; v[3] = (_Float16)lo.w;
                v[4] = (_Float16)hi.x; v[5] = (_Float16)hi.y;
                v[6] = (_Float16)hi.z; v[7] = (_Float16)hi.w;
                af[kt] = v;
            }
            f32x4 acc[2];
#pragma unroll
            for (int nt = 0; nt < 2; nt++) acc[nt] = (f32x4){0.f, 0.f, 0.f, 0.f};
#pragma unroll
            for (int kt = 0; kt < 8; kt++)
#pragma unroll
                for (int nt = 0; nt < 2; nt++)
                    acc[nt] = __builtin_amdgcn_mfma_f32_16x16x32_f16(af[kt], bfx[nt][kt], acc[nt], 0, 0, 0);
            const int rt = base + k;
            if (TOWS) {
#pragma unroll
                for (int i = 0; i < 4; i++) {
                    const size_t R = (size_t)rt * 16 + quad * 4 + i;
                    f16x2 v;
                    v[0] = (_Float16)(acc[0][i] + bb[0]);
                    v[1] = (_Float16)(acc[1][i] + bb[1]);
                    *(f16x2*)(ws + R * HH + pbase) = v;
                }
            } else {
#pragma unroll
                for (int i = 0; i < 4; i++) {
                    const size_t R = (size_t)rt * 16 + quad * 4 + i;
#pragma unroll
                    for (int nt = 0; nt < 2; nt++)
                        out[R * HH + nb + nt * 16 + c] = acc[nt][i] + bb[nt];
                }
            }
        }
        if (k + 2 < AT) XLOAD(bufA, base + k + 2)
        // ---- compute bufB (tile base+k+1) ----
        {
            f16x8 af[8];
#pragma unroll
            for (int kt = 0; kt < 8; kt++) {
                float4 lo = bufB[2 * kt], hi = bufB[2 * kt + 1];
                f16x8 v;
                v[0] = (_Float16)lo.x; v[1] = (_Float16)lo.y;
                v[2] = (_Float16)lo.z; v[3] = (_Float16)lo.w;
                v[4] = (_Float16)hi.x; v[5] = (_Float16)hi.y;
                v[6] = (_Float16)hi.z; v[7] = (_Float16)hi.w;
                af[kt] = v;
            }
            f32x4 acc[2];
#pragma unroll
            for (int nt = 0; nt < 2; nt++) acc[nt] = (f32x4){0.f, 0.f, 0.f, 0.f};
#pragma unroll
            for (int kt = 0; kt < 8; kt++)
#pragma unroll
                for (int nt = 0; nt < 2; nt++)
                    acc[nt] = __builtin_amdgcn_mfma_f32_16x16x32_f16(af[kt], bfx[nt][kt], acc[nt], 0, 0, 0);
            const int rt = base + k + 1;
            if (TOWS) {
#pragma unroll
                for (int i = 0; i < 4; i++) {
                    const size_t R = (size_t)rt * 16 + quad * 4 + i;
                    f16x2 v;
                    v[0] = (_Float16)(acc[0][i] + bb[0]);
                    v[1] = (_Float16)(acc[1][i] + bb[1]);
                    *(f16x2*)(ws + R * HH + pbase) = v;
                }
            } else {
#pragma unroll
                for (int i = 0; i < 4; i++) {
                    const size_t R = (size_t)rt * 16 + quad * 4 + i;
#pragma unroll
                    for (int nt = 0; nt < 2; nt++)
                        out[R * HH + nb + nt * 16 + c] = acc[nt][i] + bb[nt];
                }
            }
        }
    }
}

// ---------------- Kernel B: MFMA recurrence ----------------
#define SP 272  // state row pad: reads 2-way (free), writes conflict-free

// One step. CUR/NXT compile-time 0/1. XWH (ws path) / XWF (fallback) holds
// xw[T] on entry, refilled with xw[T+2] (consumed 2 steps later).
#define STEP(T, XWH, XWF, CUR, NXT)                                               \
    {                                                                             \
        f16x8 af[8]; /* branchless: fake rows read row r (harmless) */            \
        _Pragma("unroll")                                                         \
        for (int kt = 0; kt < 8; kt++)                                            \
            af[kt] = *(const f16x8*)&st[grp][CUR][r][kt * 32 + quad * 8];         \
        f32x4 accE[4], accO[4];                                                   \
        _Pragma("unroll")                                                         \
        for (int nt = 0; nt < 4; nt++) {                                          \
            float xv;                                                             \
            if constexpr (FROMWS) xv = (float)XWH[nt]; else xv = XWF[nt];         \
            accE[nt] = (f32x4){xv, 0.f, 0.f, 0.f};                                \
            accO[nt] = (f32x4){0.f, 0.f, 0.f, 0.f};                               \
        }                                                                         \
        /* prefetch xw[T+2]: alias-free vs out stores -> counted vmcnt */         \
        {                                                                         \
            const int tp = ((T) + 2 > TT - 1) ? (TT - 1) : ((T) + 2);             \
            if constexpr (FROMWS) {                                               \
                XWH = *(const f16x4*)(ws + (size_t)tp * (BB * HH) + wsoff);       \
            } else {                                                              \
                _Pragma("unroll")                                                 \
                for (int nt = 0; nt < 4; nt++)                                    \
                    XWF[nt] = out[(size_t)tp * (BB * HH) + colbase + nt * 16];    \
            }                                                                     \
        }                                                                         \
        _Pragma("unroll")                                                         \
        for (int kt = 0; kt < 4; kt++)                                            \
            _Pragma("unroll")                                                     \
            for (int nt = 0; nt < 4; nt++) {                                      \
                accE[nt] = __builtin_amdgcn_mfma_f32_16x16x32_f16(af[2 * kt],     bf[nt][2 * kt],     accE[nt], 0, 0, 0); \
                accO[nt] = __builtin_amdgcn_mfma_f32_16x16x32_f16(af[2 * kt + 1], bf[nt][2 * kt + 1], accO[nt], 0, 0, 0); \
            }                                                                     \
        const size_t obase = (size_t)(T) * (BB * HH) + colbase;                   \
        _Pragma("unroll")                                                         \
        for (int nt = 0; nt < 4; nt++) {                                          \
            h[nt] = fast_tanh(accE[nt][0] + accO[nt][0]);                         \
            out[obase + nt * 16] = h[nt];                                         \
            st[grp][NXT][quad][wg * 64 + nt * 16 + c] = (_Float16)h[nt];          \
        }                                                                         \
        asm volatile("s_waitcnt lgkmcnt(0)" ::: "memory");                        \
        __builtin_amdgcn_s_barrier();                                             \
        __builtin_amdgcn_sched_barrier(0);                                        \
    }

template <bool FROMWS>
__global__ __launch_bounds__(512, 1) void rnn_rec_mfma(const float* __restrict__ Whh,
                                                       const _Float16* __restrict__ ws,
                                                       float* __restrict__ out) {
    // [group][buf][row][col]; two independent batch groups per block
    __shared__ alignas(16) _Float16 st[2][2][4][SP];

    const int tid  = threadIdx.x;
    const int lane = tid & 63;
    const int wave = tid >> 6;        // 0..7
    const int grp  = wave >> 2;       // 0/1: which batch group
    const int wg   = wave & 3;        // N slice [wg*64, wg*64+64)
    const int c    = lane & 15;
    const int quad = lane >> 4;
    const int b0   = blockIdx.x * 8 + grp * 4;  // this group's batch rows

    f16x8 bf[4][8];
#pragma unroll
    for (int nt = 0; nt < 4; nt++) {
        const int n = wg * 64 + nt * 16 + c;
#pragma unroll
        for (int kt = 0; kt < 8; kt++) {
            const int kb = kt * 32 + quad * 8;
            f16x8 v;
#pragma unroll
            for (int j = 0; j < 8; j++)
                v[j] = (_Float16)Whh[(size_t)(kb + j) * HH + n];
            bf[nt][kt] = v;
        }
    }

    for (int i = tid; i < 2 * 2 * 4 * SP; i += 512)
        ((_Float16*)st)[i] = (_Float16)0.f;

    const int r = c >> 2;  // state row (fake rows read row r; benign)

    const size_t colbase = (size_t)(b0 + quad) * HH + wg * 64 + c;       // natural
    const size_t wsoff   = (size_t)(b0 + quad) * HH + wg * 64 + c * 4;   // permuted

    f16x4 xwhA, xwhB;
    float xwfA[4], xwfB[4];
    if constexpr (FROMWS) {
        xwhA = *(const f16x4*)(ws + wsoff);                       // t=0
        xwhB = *(const f16x4*)(ws + (size_t)BB * HH + wsoff);     // t=1
    } else {
#pragma unroll
        for (int nt = 0; nt < 4; nt++) xwfA[nt] = out[colbase + nt * 16];
#pragma unroll
        for (int nt = 0; nt < 4; nt++) xwfB[nt] = out[(size_t)BB * HH + colbase + nt * 16];
    }

    asm volatile("s_waitcnt lgkmcnt(0)" ::: "memory");
    __builtin_amdgcn_s_barrier();
    __builtin_amdgcn_sched_barrier(0);

    float h[4] = {0.f, 0.f, 0.f, 0.f};

#pragma unroll 1
    for (int t = 0; t < TT; t += 2) {
        STEP(t,     xwhA, xwfA, 0, 1)
        STEP(t + 1, xwhB, xwfB, 1, 0)
    }

    const size_t fbase = (size_t)TT * (BB * HH) + colbase;
#pragma unroll
    for (int nt = 0; nt < 4; nt++) out[fbase + nt * 16] = h[nt];
}

extern "C" void kernel_launch(void* const* d_in, const int* in_sizes, int n_in,
                              void* d_out, int out_size, void* d_ws, size_t ws_size,
                              hipStream_t stream) {
    const float* X   = (const float*)d_in[0];  // [T,B,I]
    const float* Wxh = (const float*)d_in[1];  // [I,H]
    const float* Whh = (const float*)d_in[2];  // [H,H]
    const float* bh  = (const float*)d_in[3];  // [H]
    float* out = (float*)d_out;

    const size_t need = (size_t)TT * BB * HH * sizeof(_Float16);
    if (d_ws != nullptr && ws_size >= need) {
        _Float16* ws = (_Float16*)d_ws;
        xw_gemm<true><<<dim3((TT * BB / 16) / AT), dim3(512), 0, stream>>>(X, Wxh, bh, ws, out);
        rnn_rec_mfma<true><<<dim3(BB / 8), dim3(512), 0, stream>>>(Whh, ws, out);
    } else {
        xw_gemm<false><<<dim3((TT * BB / 16) / AT), dim3(512), 0, stream>>>(X, Wxh, bh, nullptr, out);
        rnn_rec_mfma<false><<<dim3(BB / 8), dim3(512), 0, stream>>>(Whh, nullptr, out);
    }
}

// Round 5
// 984.401 us; speedup vs baseline: 1.3573x; 1.3573x over previous
//
#include <hip/hip_runtime.h>

// T=1024, B=256, I=256, H=256, fp32 in/out.
// out = outputs [T,B,H] flat, then final state [B,H].
//
// NOTE: bench dur_us carries ~258us of fixed non-kernel overhead (rd2: fused
// kernel 4415 vs total 4673). Kernel-sum is the real target.
//
// Kernel A (REWORKED, m97 structure): xw = X@W_xh + b via f16 MFMA.
//   2048 blocks x 256 thr (4 waves, 64 cols each; bfx[4][8]=128 VGPR,
//   launch_bounds(256,2) -> cap 256, 2 blocks/CU). X tiles staged to LDS
//   with global_load_lds width-16, double-buffered, vmcnt(4) counted (never
//   0) -> loads stay in flight across barriers. Source-side XOR swizzle
//   (chunk ^= row&7, involution) + same XOR on ds_read side -> uniform
//   bank use. This kills the per-wave load-latency serialization that
//   pinned A at ~290us (floor ~70us).
// Kernel B: REVERTED to round-3 version verbatim (558us proven; round-4's
//   8-wave barrier-coupled variant serialized shared pipes -> 787us).

#define TT 1024
#define BB 256
#define HH 256

typedef __attribute__((ext_vector_type(8))) _Float16 f16x8;
typedef __attribute__((ext_vector_type(4))) _Float16 f16x4;
typedef __attribute__((ext_vector_type(4))) float f32x4;

__device__ __forceinline__ float fast_tanh(float x) {
    float e = __expf(2.0f * x);
    return 1.0f - 2.0f * __builtin_amdgcn_rcpf(e + 1.0f);
}

#define PACK8(DST, LO, HI)                                                        \
    {                                                                             \
        f16x8 v_;                                                                 \
        v_[0] = (_Float16)(LO).x; v_[1] = (_Float16)(LO).y;                       \
        v_[2] = (_Float16)(LO).z; v_[3] = (_Float16)(LO).w;                       \
        v_[4] = (_Float16)(HI).x; v_[5] = (_Float16)(HI).y;                       \
        v_[6] = (_Float16)(HI).z; v_[7] = (_Float16)(HI).w;                       \
        DST = v_;                                                                 \
    }

// ---------------- Kernel A: xw = X @ W_xh + b ----------------
#define AT 8  // row-tiles per block; grid = 16384/AT = 2048 blocks

// Stage tile RT into LDS buffer BUF. Wave w stages rows 4w..4w+3, one
// global_load_lds (64 lanes x 16B = one 1KB row) per row. LDS dest is
// wave-uniform base + lane*16 (linear); the SOURCE chunk is pre-swizzled
// (lane ^ (row&7)) so the read side can use the same XOR.
#define STAGE(BUF, RT)                                                            \
    {                                                                             \
        _Pragma("unroll")                                                         \
        for (int i_ = 0; i_ < 4; i_++) {                                          \
            const int r_ = wave * 4 + i_;                                         \
            const float* g_ =                                                     \
                X + ((size_t)(RT)*16 + r_) * HH + ((lane ^ (r_ & 7)) << 2);       \
            __builtin_amdgcn_global_load_lds(                                     \
                (const __attribute__((address_space(1))) void*)g_,                \
                (__attribute__((address_space(3))) void*)&xs[BUF][r_][0],         \
                16, 0, 0);                                                        \
        }                                                                         \
    }

template <bool TOWS>
__global__ __launch_bounds__(256, 2) void xw_gemm(const float* __restrict__ X,
                                                  const float* __restrict__ W,
                                                  const float* __restrict__ bh,
                                                  _Float16* __restrict__ ws,
                                                  float* __restrict__ out) {
    __shared__ float xs[2][16][256];  // 2 x 16KB, linear (swizzled content)

    const int tid  = threadIdx.x;
    const int lane = tid & 63;
    const int wave = tid >> 6;        // 0..3, cols [wave*64, wave*64+64)
    const int c    = lane & 15;
    const int quad = lane >> 4;

    // B frags: bfx[nt][kt][j] = W[kt*32+quad*8+j][wave*64+nt*16+c]  (128 VGPR)
    f16x8 bfx[4][8];
#pragma unroll
    for (int nt = 0; nt < 4; nt++) {
        const int n = wave * 64 + nt * 16 + c;
#pragma unroll
        for (int kt = 0; kt < 8; kt++) {
            const int kb = kt * 32 + quad * 8;
            f16x8 v;
#pragma unroll
            for (int j = 0; j < 8; j++)
                v[j] = (_Float16)W[(size_t)(kb + j) * HH + n];
            bfx[nt][kt] = v;
        }
    }
    float bb[4];
#pragma unroll
    for (int nt = 0; nt < 4; nt++) bb[nt] = bh[wave * 64 + nt * 16 + c];

    // read-side swizzle: logical chunk (8kt + 2q [+1]) lives at chunk^ (c&7)
    const int s  = c & 7;
    const int t0 = (quad << 1) ^ s;       // lo-half chunk position (per kt: +8kt)
    const int t1 = t0 ^ 1;                // hi-half

    const int base = blockIdx.x * AT;
    int cur = 0;

    STAGE(0, base)

#pragma unroll 1
    for (int j = 0; j < AT; j++) {
        const int rt  = base + j;
        const int nrt = (j + 1 < AT) ? rt + 1 : rt;  // clamp: restage (other buf)

        asm volatile("s_barrier" ::: "memory");      // B1: prev reads done
        STAGE(cur ^ 1, nrt)
        asm volatile("s_waitcnt vmcnt(4)" ::: "memory");  // tile-j loads done
        asm volatile("s_barrier" ::: "memory");      // B2: tile-j visible to all
        __builtin_amdgcn_sched_barrier(0);

        const float* bp0 = &xs[cur][c][t0 << 2];
        const float* bp1 = &xs[cur][c][t1 << 2];
        f16x8 af[8];
#pragma unroll
        for (int kt = 0; kt < 8; kt++) {
            float4 lo = *(const float4*)(bp0 + kt * 32);
            float4 hi = *(const float4*)(bp1 + kt * 32);
            PACK8(af[kt], lo, hi)
        }

        f32x4 acc[4];
#pragma unroll
        for (int nt = 0; nt < 4; nt++) acc[nt] = (f32x4){0.f, 0.f, 0.f, 0.f};
#pragma unroll
        for (int kt = 0; kt < 8; kt++)
#pragma unroll
            for (int nt = 0; nt < 4; nt++)
                acc[nt] = __builtin_amdgcn_mfma_f32_16x16x32_f16(af[kt], bfx[nt][kt], acc[nt], 0, 0, 0);

        // D: col = c, row = quad*4 + i
        const size_t Rb = (size_t)rt * 16 + quad * 4;
        if (TOWS) {
            // permuted f16 layout: col n=wave*64+nt*16+c -> p = wave*64+c*4+nt
            // -> this lane's 4 nt values are ONE f16x4 (8B) store per row.
#pragma unroll
            for (int i = 0; i < 4; i++) {
                f16x4 v;
#pragma unroll
                for (int nt = 0; nt < 4; nt++)
                    v[nt] = (_Float16)(acc[nt][i] + bb[nt]);
                *(f16x4*)(ws + (Rb + i) * HH + wave * 64 + c * 4) = v;
            }
        } else {
#pragma unroll
            for (int i = 0; i < 4; i++)
#pragma unroll
                for (int nt = 0; nt < 4; nt++)
                    out[(Rb + i) * HH + wave * 64 + nt * 16 + c] = acc[nt][i] + bb[nt];
        }
        cur ^= 1;
    }
}

// ---------------- Kernel B: MFMA recurrence (round-3, proven 558us) ----------------
#define SP 272  // state row pad: reads 2-way (free), writes conflict-free

#define STEP(T, XWH, XWF, CUR, NXT)                                               \
    {                                                                             \
        f16x8 af[8]; /* branchless: fake rows read row r (harmless) */            \
        _Pragma("unroll")                                                         \
        for (int kt = 0; kt < 8; kt++)                                            \
            af[kt] = *(const f16x8*)&st[CUR][r][kt * 32 + quad * 8];              \
        f32x4 accE[4], accO[4];                                                   \
        _Pragma("unroll")                                                         \
        for (int nt = 0; nt < 4; nt++) {                                          \
            float xv;                                                             \
            if constexpr (FROMWS) xv = (float)XWH[nt]; else xv = XWF[nt];         \
            accE[nt] = (f32x4){xv, 0.f, 0.f, 0.f};                                \
            accO[nt] = (f32x4){0.f, 0.f, 0.f, 0.f};                               \
        }                                                                         \
        /* prefetch xw[T+2]: alias-free vs out stores -> counted vmcnt */         \
        {                                                                         \
            const int tp = ((T) + 2 > TT - 1) ? (TT - 1) : ((T) + 2);             \
            if constexpr (FROMWS) {                                               \
                XWH = *(const f16x4*)(ws + (size_t)tp * (BB * HH) + wsoff);       \
            } else {                                                              \
                _Pragma("unroll")                                                 \
                for (int nt = 0; nt < 4; nt++)                                    \
                    XWF[nt] = out[(size_t)tp * (BB * HH) + colbase + nt * 16];    \
            }                                                                     \
        }                                                                         \
        _Pragma("unroll")                                                         \
        for (int kt = 0; kt < 4; kt++)                                            \
            _Pragma("unroll")                                                     \
            for (int nt = 0; nt < 4; nt++) {                                      \
                accE[nt] = __builtin_amdgcn_mfma_f32_16x16x32_f16(af[2 * kt],     bf[nt][2 * kt],     accE[nt], 0, 0, 0); \
                accO[nt] = __builtin_amdgcn_mfma_f32_16x16x32_f16(af[2 * kt + 1], bf[nt][2 * kt + 1], accO[nt], 0, 0, 0); \
            }                                                                     \
        const size_t obase = (size_t)(T) * (BB * HH) + colbase;                   \
        _Pragma("unroll")                                                         \
        for (int nt = 0; nt < 4; nt++) {                                          \
            h[nt] = fast_tanh(accE[nt][0] + accO[nt][0]);                         \
            out[obase + nt * 16] = h[nt];                                         \
            st[NXT][quad][wave * 64 + nt * 16 + c] = (_Float16)h[nt];             \
        }                                                                         \
        asm volatile("s_waitcnt lgkmcnt(0)" ::: "memory");                        \
        __builtin_amdgcn_s_barrier();                                             \
        __builtin_amdgcn_sched_barrier(0);                                        \
    }

template <bool FROMWS>
__global__ __launch_bounds__(256, 1) void rnn_rec_mfma(const float* __restrict__ Whh,
                                                       const _Float16* __restrict__ ws,
                                                       float* __restrict__ out) {
    __shared__ alignas(16) _Float16 st[2][4][SP];

    const int tid  = threadIdx.x;
    const int lane = tid & 63;
    const int wave = tid >> 6;        // N slice [wave*64, wave*64+64)
    const int c    = lane & 15;
    const int quad = lane >> 4;
    const int b0   = blockIdx.x * 4;  // batch rows b0..b0+3 at m = 4*r

    f16x8 bf[4][8];
#pragma unroll
    for (int nt = 0; nt < 4; nt++) {
        const int n = wave * 64 + nt * 16 + c;
#pragma unroll
        for (int kt = 0; kt < 8; kt++) {
            const int kb = kt * 32 + quad * 8;
            f16x8 v;
#pragma unroll
            for (int j = 0; j < 8; j++)
                v[j] = (_Float16)Whh[(size_t)(kb + j) * HH + n];
            bf[nt][kt] = v;
        }
    }

    for (int i = tid; i < 2 * 4 * SP; i += 256)
        ((_Float16*)st)[i] = (_Float16)0.f;

    const int r = c >> 2;  // state row (fake rows read row r; benign)

    const size_t colbase = (size_t)(b0 + quad) * HH + wave * 64 + c;       // natural
    const size_t wsoff   = (size_t)(b0 + quad) * HH + wave * 64 + c * 4;   // permuted

    f16x4 xwhA, xwhB;
    float xwfA[4], xwfB[4];
    if constexpr (FROMWS) {
        xwhA = *(const f16x4*)(ws + wsoff);                       // t=0
        xwhB = *(const f16x4*)(ws + (size_t)BB * HH + wsoff);     // t=1
    } else {
#pragma unroll
        for (int nt = 0; nt < 4; nt++) xwfA[nt] = out[colbase + nt * 16];
#pragma unroll
        for (int nt = 0; nt < 4; nt++) xwfB[nt] = out[(size_t)BB * HH + colbase + nt * 16];
    }

    asm volatile("s_waitcnt lgkmcnt(0)" ::: "memory");
    __builtin_amdgcn_s_barrier();
    __builtin_amdgcn_sched_barrier(0);

    float h[4] = {0.f, 0.f, 0.f, 0.f};

#pragma unroll 1
    for (int t = 0; t < TT; t += 2) {
        STEP(t,     xwhA, xwfA, 0, 1)
        STEP(t + 1, xwhB, xwfB, 1, 0)
    }

    const size_t fbase = (size_t)TT * (BB * HH) + colbase;
#pragma unroll
    for (int nt = 0; nt < 4; nt++) out[fbase + nt * 16] = h[nt];
}

extern "C" void kernel_launch(void* const* d_in, const int* in_sizes, int n_in,
                              void* d_out, int out_size, void* d_ws, size_t ws_size,
                              hipStream_t stream) {
    const float* X   = (const float*)d_in[0];  // [T,B,I]
    const float* Wxh = (const float*)d_in[1];  // [I,H]
    const float* Whh = (const float*)d_in[2];  // [H,H]
    const float* bh  = (const float*)d_in[3];  // [H]
    float* out = (float*)d_out;

    const size_t need = (size_t)TT * BB * HH * sizeof(_Float16);
    if (d_ws != nullptr && ws_size >= need) {
        _Float16* ws = (_Float16*)d_ws;
        xw_gemm<true><<<dim3((TT * BB / 16) / AT), dim3(256), 0, stream>>>(X, Wxh, bh, ws, out);
        rnn_rec_mfma<true><<<dim3(BB / 4), dim3(256), 0, stream>>>(Whh, ws, out);
    } else {
        xw_gemm<false><<<dim3((TT * BB / 16) / AT), dim3(256), 0, stream>>>(X, Wxh, bh, nullptr, out);
        rnn_rec_mfma<false><<<dim3(BB / 4), dim3(256), 0, stream>>>(Whh, nullptr, out);
    }
}